// Round 1
// baseline (172.052 us; speedup 1.0000x reference)
//
#include <hip/hip_runtime.h>

// CT parallel-beam pixel-driven back-projection. Static geometry.
// Two-kernel design:
//   prep_kernel (R16): one block per (group g, batch b). Each thread computes
//     bins i..i+3 of BOTH fused opposing-view pair arrays —
//     A = views (g, g+360), B = (g+180, g+540) — entry (D,S) fp16 with
//     S[i] = fwd[i] + rev[735-i], D = S[i+1]-S[i], and stores them
//     INTERLEAVED: entry j is 8 B {A(D,S), B(D,S)}. float4 loads,
//     2x dwordx4 stores.
//   backproject_dma_kernel: staging = pure global_load_lds DMA (16 B) into
//     a 4-deep LDS ring. R15 reorder: issue(p+1) BEFORE groups(p), barrier
//     AFTER — the __syncthreads vmcnt(0) drain then waits on a DMA aged by
//     ~2800 cyc of compute (free), not a fresh one.
//   R16: visit() was 2x ds_read_b32 at i0 and i0+PADDET (same i0). rocprof
//     showed the kernel LDS-issue-bound: 46080 wave-reads/CU over 278k cyc
//     = 6.0 cyc/read = the ds_read_b32 issue throughput (addr-phase limited,
//     42 B/cyc << 112 B/cyc LDS data ceiling). Interleaved (A,B) layout
//     fuses the pair into ONE ds_read_b64 — same bytes, half the LDS
//     instructions. Ring/DMA/barrier structure identical (layout-agnostic).
// Symmetries (verified R7-R12): view quad {v,v+180,v+360,v+540} x pixel
// rotation orbit; 4 visits u = C+-g1, C+-g2 per group serve 16 pixel-views.
// Fallback: if ws_size < needed, launch the proven R12 kernel (161 us).
#define BATCH 8
#define NVIEW 720
#define NPAIR 360
#define NGRP  180
#define NDET  736
#define IMGH  512
#define IMGW  512

#define DANG_F  ((float)(6.283185307179586 / 720.0))
#define RATIO_F ((float)(0.006641 / 0.0066))
#define UCENTER ((float)((NDET - 1) * 0.5))

#define PADDET 768   // padded entries per group (8 B each; 1024B DMA tiling)
#define ITER_BYTES 12288  // 2 groups x 768 entries x 8 B per iteration
#define WS_BYTES ((size_t)BATCH * NGRP * PADDET * 8)

typedef float  v2f __attribute__((ext_vector_type(2)));
typedef __fp16 v2h __attribute__((ext_vector_type(2)));
typedef __fp16 v4h __attribute__((ext_vector_type(4)));

// ---------------- prep kernel (R16: interleaved A/B) ----------------
// grid (180, 8), block 192 (threads 0..183 active). Group g: pairA rows
// (g, g+360), pairB rows (g+180, g+540) — all in [0,720) of batch b.
// Thread owns bins i..i+3 of both arrays. Overshoot: fwd[i+4] at i=732
// reads next row elem 0 (fwd rows <= 359, next row exists in-batch);
// rev[-1] reads prev row last elem (rev rows >= 360). Both land only in
// bin 735's D, never read (i0 <= 731). Pad [736,768) unwritten, DMA'd
// but never read.
__global__ __launch_bounds__(192) void prep_kernel(
    const float* __restrict__ proj, v2h* __restrict__ ws)
{
    const int t = threadIdx.x;
    if (t >= 184) return;
    const int g = blockIdx.x;
    const int b = blockIdx.y;
    const int i = 4 * t;
    const float* __restrict__ fA = proj + ((size_t)b * NVIEW + g) * NDET;
    const float* __restrict__ rA = fA + (size_t)NPAIR * NDET;   // g+360
    const float* __restrict__ fB = fA + (size_t)NGRP * NDET;    // g+180
    const float* __restrict__ rB = fB + (size_t)NPAIR * NDET;   // g+540
    const float4 fa4 = *(const float4*)(fA + i);
    const float  fa1 = fA[i + 4];
    const float4 ra4 = *(const float4*)(rA + (732 - i));  // taps i..i+3=(w,z,y,x)
    const float  ra1 = rA[731 - i];                       // tap i+4
    const float4 fb4 = *(const float4*)(fB + i);
    const float  fb1 = fB[i + 4];
    const float4 rb4 = *(const float4*)(rB + (732 - i));
    const float  rb1 = rB[731 - i];
    const float sa0 = fa4.x + ra4.w;
    const float sa1 = fa4.y + ra4.z;
    const float sa2 = fa4.z + ra4.y;
    const float sa3 = fa4.w + ra4.x;
    const float sa4 = fa1 + ra1;
    const float sb0 = fb4.x + rb4.w;
    const float sb1 = fb4.y + rb4.z;
    const float sb2 = fb4.z + rb4.y;
    const float sb3 = fb4.w + rb4.x;
    const float sb4 = fb1 + rb1;
    const v2h nA0 = __builtin_amdgcn_cvt_pkrtz(sa1 - sa0, sa0);   // (D, S)
    const v2h nA1 = __builtin_amdgcn_cvt_pkrtz(sa2 - sa1, sa1);
    const v2h nA2 = __builtin_amdgcn_cvt_pkrtz(sa3 - sa2, sa2);
    const v2h nA3 = __builtin_amdgcn_cvt_pkrtz(sa4 - sa3, sa3);
    const v2h nB0 = __builtin_amdgcn_cvt_pkrtz(sb1 - sb0, sb0);
    const v2h nB1 = __builtin_amdgcn_cvt_pkrtz(sb2 - sb1, sb1);
    const v2h nB2 = __builtin_amdgcn_cvt_pkrtz(sb3 - sb2, sb2);
    const v2h nB3 = __builtin_amdgcn_cvt_pkrtz(sb4 - sb3, sb3);
    struct alignas(16) H8 { v2h a0, b0, a1, b1; };  // entries j, j+1
    v2h* __restrict__ dst =
        ws + ((size_t)b * NGRP + g) * (2 * PADDET) + 2 * i;
    *(H8*)(dst)     = H8{nA0, nB0, nA1, nB1};
    *(H8*)(dst + 4) = H8{nA2, nB2, nA3, nB3};
}

// One u value: single ds_read_b64 pulls interleaved {A(D,S), B(D,S)};
// 2-view interp of A into accA and B into accB via packed fdot2.
__device__ __forceinline__ void visit(const v2h* __restrict__ L,
                                      float u, float& accA, float& accB) {
    const int   i0 = (int)u;                      // u in [3.9, 731.1] always
    const float fr = __builtin_amdgcn_fractf(u);
    const v2h wv = __builtin_amdgcn_cvt_pkrtz(fr, 1.0f);
    const v4h AB = *(const v4h*)(L + 2 * i0);     // ds_read_b64, 8B-aligned
    const v2h A = {AB.x, AB.y};
    const v2h B = {AB.z, AB.w};
    accA = __builtin_amdgcn_fdot2(A, wv, accA, false);   // S + fr*D
    accB = __builtin_amdgcn_fdot2(B, wv, accB, false);
}

// ---------------- main kernel (DMA path) ----------------
// 512 threads = 8 waves; wave = one h row of the top-left quadrant, lanes =
// 64 consecutive w; thread owns two rotation orbits (w0, w0+128).
// Grid 512 = exactly 2 blocks/CU. Iteration p stages groups (2p, 2p+1):
// 12288 B = 12 slices of 1024 B (64 lanes x 16 B); wave w takes slice w,
// waves 0..3 also take slice 8+w (wave-uniform branch).
// Pipeline (R15): issue(p+1) -> groups(p) -> __syncthreads. The barrier's
// vmcnt(0) drain waits on a DMA aged by groups(p) (~2800 cyc) -> free.
// groups(p)'s slot p&3 was drained by iteration p-1's end barrier.
// Ring safety: issue(p+1) writes slot (p+1)&3 while groups(p) reads p&3;
// prior content of slot (p+1)&3 (iter p-3) was last read in groups(p-3),
// sealed by that iteration's end barrier, which all waves have passed.
// Bounds check proven unnecessary: |g1|,|g2| <= 363.6 < 367.5.
__global__ __launch_bounds__(512, 4) void backproject_dma_kernel(
    const v2h* __restrict__ ws, float* __restrict__ out)
{
    __shared__ alignas(16) v2h lds4[4][2 * 2 * PADDET];  // 4 x 12288 B ring
    __shared__ v2f cs[NGRP];

    const int tid  = threadIdx.x;
    const int wave = tid >> 6;
    const int lane = tid & 63;

    if (tid < NGRP) {
        float s, c;
        sincosf((float)tid * DANG_F, &s, &c);
        cs[tid] = (v2f){c * RATIO_F, s * RATIO_F};   // sealed by 1st barrier
    }

    const int b  = blockIdx.z;
    const int h  = (int)blockIdx.y * 8 + wave;           // [0, 256)
    const int w0 = (int)blockIdx.x * 64 + lane;          // [0, 128)

    const float px = (float)w0 - (float)(IMGW - 1) * 0.5f;
    const float py = (float)(IMGH - 1) * 0.5f - (float)h;

    const char* __restrict__ wsb =
        (const char*)(ws + (size_t)b * NGRP * 2 * PADDET);

    float a0 = 0.f, a1 = 0.f, a2 = 0.f, a3 = 0.f;
    float b0 = 0.f, b1 = 0.f, b2 = 0.f, b3 = 0.f;

    auto issue = [&](int p) {
        const char* g0 = wsb + (size_t)p * ITER_BYTES;
        char* l0 = (char*)&lds4[p & 3][0];
        __builtin_amdgcn_global_load_lds(
            (const __attribute__((address_space(1))) void*)
                (g0 + wave * 1024 + lane * 16),
            (__attribute__((address_space(3))) void*)(l0 + wave * 1024),
            16, 0, 0);
        if (wave < 4) {
            const int s = 8 + wave;
            __builtin_amdgcn_global_load_lds(
                (const __attribute__((address_space(1))) void*)
                    (g0 + s * 1024 + lane * 16),
                (__attribute__((address_space(3))) void*)(l0 + s * 1024),
                16, 0, 0);
        }
    };

    auto groups = [&](int p) {
        const v2h* __restrict__ L4 = &lds4[p & 3][0];
#pragma unroll
        for (int sub = 0; sub < 2; ++sub) {
            const v2h* __restrict__ L = L4 + sub * (2 * PADDET);
            const v2f t = cs[2 * p + sub];
            // (g1, g2) = px*(c, -s) + py*(s, c)  -- packed fp32
            const v2f m1 = {t.x, -t.y};
            const v2f m2 = {t.y, t.x};
            const v2f pxv = {px, px};
            const v2f pyv = {py, py};
            const v2f gvec = __builtin_elementwise_fma(pxv, m1, pyv * m2);
            const v2f cc = {UCENTER, UCENTER};
            const v2f up = cc + gvec;      // rep0 (C+g1, C+g2)
            const v2f um = cc - gvec;      // rep0 (C-g1, C-g2)
            const v2f dd = {128.0f, 128.0f};
            const v2f dm = dd * m1;        // 128*(cx, -sy)
            const v2f vp = up + dm;        // rep1
            const v2f vm = um - dm;        // rep1

            visit(L, up.x, a0, a1);   // +g1: A->q0, B->q1
            visit(L, um.x, a2, a3);   // -g1: A->q2, B->q3
            visit(L, up.y, a3, a0);   // +g2: A->q3, B->q0
            visit(L, um.y, a1, a2);   // -g2: A->q1, B->q2
            visit(L, vp.x, b0, b1);
            visit(L, vm.x, b2, b3);
            visit(L, vp.y, b3, b0);
            visit(L, vm.y, b1, b2);
        }
    };

    issue(0);
    __syncthreads();   // drains issue(0) (once) + seals cs[]
    for (int p = 0; p < 90; ++p) {
        if (p + 1 < 90) issue(p + 1);
        groups(p);
        if (p + 1 < 90) __syncthreads();   // drain aged DMA; RW separation
    }

    float* __restrict__ o = out + (size_t)b * IMGH * IMGW;
    const int hm  = (IMGH - 1) - h;
    const int w1  = w0 + 128;
    const int wm0 = (IMGW - 1) - w0;
    const int wm1 = (IMGW - 1) - w1;
    o[h   * IMGW + w0 ] = a0 * DANG_F;
    o[wm0 * IMGW + h  ] = a1 * DANG_F;
    o[hm  * IMGW + wm0] = a2 * DANG_F;
    o[w0  * IMGW + hm ] = a3 * DANG_F;
    o[h   * IMGW + w1 ] = b0 * DANG_F;
    o[wm1 * IMGW + h  ] = b1 * DANG_F;
    o[hm  * IMGW + wm1] = b2 * DANG_F;
    o[w1  * IMGW + hm ] = b3 * DANG_F;
}

// ---------------- fallback (R12, proven 161 us) ----------------
struct Stage { float4 f4, r4; float f1, r1; };

__device__ __forceinline__ void fb_load(const float* __restrict__ sino,
                                        int k, int t, Stage& S) {
    if (t < 368) {
        const int p  = (t >= 184);
        const int i  = 4 * (t - 184 * p);
        const int vf = k + 180 * p;
        const float* __restrict__ fwd = sino + vf * NDET;
        const float* __restrict__ rev = sino + (vf + NPAIR) * NDET;
        S.f4 = *(const float4*)(fwd + i);
        S.f1 = fwd[i + 4];
        S.r4 = *(const float4*)(rev + (732 - i));
        S.r1 = rev[731 - i];
    }
}

__device__ __forceinline__ void fb_write(v2h* __restrict__ L, int t,
                                         const Stage& S) {
    if (t < 368) {
        const int p = (t >= 184);
        const int i = 4 * (t - 184 * p);
        const float s0 = S.f4.x + S.r4.w;
        const float s1 = S.f4.y + S.r4.z;
        const float s2 = S.f4.z + S.r4.y;
        const float s3 = S.f4.w + S.r4.x;
        const float s4 = S.f1 + S.r1;
        const v2h n0 = __builtin_amdgcn_cvt_pkrtz(s1 - s0, s0);
        const v2h n1 = __builtin_amdgcn_cvt_pkrtz(s2 - s1, s1);
        const v2h n2 = __builtin_amdgcn_cvt_pkrtz(s3 - s2, s2);
        const v2h n3 = __builtin_amdgcn_cvt_pkrtz(s4 - s3, s3);
        struct alignas(16) H4 { v2h a, b, c, d; };
        *(H4*)(L + p * NDET + i) = H4{n0, n1, n2, n3};
    }
}

__device__ __forceinline__ void fb_visit(const v2h* __restrict__ L,
                                         float u, float& accA, float& accB) {
    const int   i0 = (int)u;
    const float fr = __builtin_amdgcn_fractf(u);
    const v2h wv = __builtin_amdgcn_cvt_pkrtz(fr, 1.0f);
    const v2h A = L[i0];
    const v2h B = L[i0 + NDET];
    accA = __builtin_amdgcn_fdot2(A, wv, accA, false);
    accB = __builtin_amdgcn_fdot2(B, wv, accB, false);
}

__global__ __launch_bounds__(512, 4) void backproject_fb_kernel(
    const float* __restrict__ proj, float* __restrict__ out)
{
    __shared__ alignas(16) v2h lds[2][2][2 * NDET];
    __shared__ v2f cs[NGRP];

    const int tid = threadIdx.x;
    if (tid < NGRP) {
        float s, c;
        sincosf((float)tid * DANG_F, &s, &c);
        cs[tid] = (v2f){c * RATIO_F, s * RATIO_F};
    }

    const int b    = blockIdx.z;
    const int lane = tid & 63;
    const int h    = (int)blockIdx.y * 8 + (tid >> 6);
    const int w0   = (int)blockIdx.x * 64 + lane;

    const float px = (float)w0 - (float)(IMGW - 1) * 0.5f;
    const float py = (float)(IMGH - 1) * 0.5f - (float)h;

    const float* __restrict__ sino = proj + (size_t)b * NVIEW * NDET;

    float a0 = 0.f, a1 = 0.f, a2 = 0.f, a3 = 0.f;
    float b0 = 0.f, b1 = 0.f, b2 = 0.f, b3 = 0.f;

    Stage s0 = {}, s1 = {};
    fb_load(sino, 0, tid, s0);
    fb_load(sino, 1, tid, s1);
    fb_write(lds[0][0], tid, s0);
    fb_write(lds[0][1], tid, s1);
    fb_load(sino, 2, tid, s0);
    fb_load(sino, 3, tid, s1);
    __syncthreads();

    for (int gg = 0; gg < NGRP; gg += 2) {
        const int buf = (gg >> 1) & 1;
#pragma unroll
        for (int sub = 0; sub < 2; ++sub) {
            const v2h* __restrict__ L = lds[buf][sub];
            const v2f t = cs[gg + sub];
            const v2f m1 = {t.x, -t.y};
            const v2f m2 = {t.y, t.x};
            const v2f pxv = {px, px};
            const v2f pyv = {py, py};
            const v2f gvec = __builtin_elementwise_fma(pxv, m1, pyv * m2);
            const v2f cc = {UCENTER, UCENTER};
            const v2f up = cc + gvec;
            const v2f um = cc - gvec;
            const v2f dd = {128.0f, 128.0f};
            const v2f dm = dd * m1;
            const v2f vp = up + dm;
            const v2f vm = um - dm;

            fb_visit(L, up.x, a0, a1);
            fb_visit(L, um.x, a2, a3);
            fb_visit(L, up.y, a3, a0);
            fb_visit(L, um.y, a1, a2);
            fb_visit(L, vp.x, b0, b1);
            fb_visit(L, vm.x, b2, b3);
            fb_visit(L, vp.y, b3, b0);
            fb_visit(L, vm.y, b1, b2);
        }
        if (gg < NGRP - 2) {
            fb_write(lds[buf ^ 1][0], tid, s0);
            fb_write(lds[buf ^ 1][1], tid, s1);
            if (gg < NGRP - 4) {
                fb_load(sino, gg + 4, tid, s0);
                fb_load(sino, gg + 5, tid, s1);
            }
            __syncthreads();
        }
    }

    float* __restrict__ o = out + (size_t)b * IMGH * IMGW;
    const int hm  = (IMGH - 1) - h;
    const int w1  = w0 + 128;
    const int wm0 = (IMGW - 1) - w0;
    const int wm1 = (IMGW - 1) - w1;
    o[h   * IMGW + w0 ] = a0 * DANG_F;
    o[wm0 * IMGW + h  ] = a1 * DANG_F;
    o[hm  * IMGW + wm0] = a2 * DANG_F;
    o[w0  * IMGW + hm ] = a3 * DANG_F;
    o[h   * IMGW + w1 ] = b0 * DANG_F;
    o[wm1 * IMGW + h  ] = b1 * DANG_F;
    o[hm  * IMGW + wm1] = b2 * DANG_F;
    o[w1  * IMGW + hm ] = b3 * DANG_F;
}

extern "C" void kernel_launch(void* const* d_in, const int* in_sizes, int n_in,
                              void* d_out, int out_size, void* d_ws, size_t ws_size,
                              hipStream_t stream) {
    const float* proj = (const float*)d_in[0];
    float* out = (float*)d_out;

    if (ws_size >= WS_BYTES) {
        v2h* ws = (v2h*)d_ws;
        prep_kernel<<<dim3(NGRP, BATCH), 192, 0, stream>>>(proj, ws);
        backproject_dma_kernel<<<dim3(2, 32, BATCH), 512, 0, stream>>>(ws, out);
    } else {
        backproject_fb_kernel<<<dim3(2, 32, BATCH), 512, 0, stream>>>(proj, out);
    }
}